// Round 15
// baseline (139.026 us; speedup 1.0000x reference)
//
#include <hip/hip_runtime.h>
#include <hip/hip_bf16.h>

typedef __attribute__((ext_vector_type(8))) short short8;           // 8 bf16 (MFMA operand)
typedef __attribute__((ext_vector_type(8))) unsigned short ushort8; // data movement
typedef __attribute__((ext_vector_type(4))) float f32x4;
typedef __attribute__((ext_vector_type(4))) unsigned short u16x4;

#define MFMA16(a, b, c) __builtin_amdgcn_mfma_f32_16x16x32_bf16(a, b, c, 0, 0, 0)

__device__ __forceinline__ unsigned short f2bf(float f) {
  union { float f; unsigned u; } x; x.f = f;
  unsigned r = x.u + 0x7FFFu + ((x.u >> 16) & 1u);  // RNE
  return (unsigned short)(r >> 16);
}
__device__ __forceinline__ float bf2f(unsigned short h) {
  union { unsigned u; float f; } x; x.u = ((unsigned)h) << 16;
  return x.f;
}
__device__ __forceinline__ void load_lds16(const void* g, void* l) {
  __builtin_amdgcn_global_load_lds((const __attribute__((address_space(1))) void*)g,
                                   (__attribute__((address_space(3))) void*)l, 16, 0, 0);
}

// ---------------------------------------------------------------------------
// 1) fp32 -> bf16 conversion for x, w_qkv, w_proj
// ---------------------------------------------------------------------------
__global__ __launch_bounds__(256) void convert_all(
    const float* __restrict__ x, const float* __restrict__ wqkv, const float* __restrict__ wproj,
    unsigned short* __restrict__ xb, unsigned short* __restrict__ wqkvb,
    unsigned short* __restrict__ wprojb) {
  int i = blockIdx.x * 256 + threadIdx.x;
  const float4* src; unsigned short* dst; int o;
  if (i < 1048576) { src = (const float4*)x; dst = xb; o = i; }
  else if (i < 1048576 + 786432) { src = (const float4*)wqkv; dst = wqkvb; o = i - 1048576; }
  else { src = (const float4*)wproj; dst = wprojb; o = i - (1048576 + 786432); }
  float4 v = src[o];
  u16x4 r; r.x = f2bf(v.x); r.y = f2bf(v.y); r.z = f2bf(v.z); r.w = f2bf(v.w);
  *(u16x4*)(dst + (size_t)o * 4) = r;
}

// ---------------------------------------------------------------------------
// 2) NT GEMM: C[M,N] = A[M,K]*B[N,K]^T + bias. 128x128 tile, BK=32, 4 waves.
//    MODE 0: fp32 C out (out-proj).
//    MODE 1: QKV fused epilogue — q/k parts: RMSNorm (fp32) -> bf16 qkv;
//            v part: direct transpose-store to vT[bh][d][n] (skip qkv write).
// ---------------------------------------------------------------------------
template <int MODE>
__global__ __launch_bounds__(256) void gemm_nt(
    const unsigned short* __restrict__ A, const unsigned short* __restrict__ Bm,
    const float* __restrict__ bias, void* __restrict__ Cout, int M, int N, int K,
    const float* __restrict__ qnw, const float* __restrict__ knw,
    unsigned short* __restrict__ vT) {
  __shared__ unsigned short As[128 * 32];
  __shared__ unsigned short Bs[128 * 32];
  const int t = threadIdx.x, w = t >> 6, l = t & 63;
  const int la = l & 15, lg = l >> 4;
  const int wm = w >> 1, wn = w & 1;
  const int m0 = blockIdx.y * 128, n0 = blockIdx.x * 128;

  const int r0 = t >> 2, c0 = (t & 3) ^ ((r0 >> 1) & 3);
  const int r1 = r0 + 64, c1 = (t & 3) ^ ((r1 >> 1) & 3);
  const unsigned short* a0 = A + (size_t)(m0 + r0) * K + c0 * 8;
  const unsigned short* a1 = A + (size_t)(m0 + r1) * K + c1 * 8;
  const unsigned short* b0 = Bm + (size_t)(n0 + r0) * K + c0 * 8;
  const unsigned short* b1 = Bm + (size_t)(n0 + r1) * K + c1 * 8;
  char* ldsA0 = (char*)As + w * 1024;
  char* ldsA1 = (char*)As + w * 1024 + 4096;
  char* ldsB0 = (char*)Bs + w * 1024;
  char* ldsB1 = (char*)Bs + w * 1024 + 4096;

  f32x4 acc[4][4] = {};
  int offA[4], offB[4];
#pragma unroll
  for (int f = 0; f < 4; ++f) {
    int ra = wm * 64 + f * 16 + la;
    offA[f] = ra * 64 + ((lg ^ ((ra >> 1) & 3)) * 16);
    int rb = wn * 64 + f * 16 + la;
    offB[f] = rb * 64 + ((lg ^ ((rb >> 1) & 3)) * 16);
  }

  for (int kt = 0; kt < K; kt += 32) {
    __syncthreads();
    load_lds16(a0 + kt, ldsA0);
    load_lds16(a1 + kt, ldsA1);
    load_lds16(b0 + kt, ldsB0);
    load_lds16(b1 + kt, ldsB1);
    __syncthreads();
    short8 af[4], bf[4];
#pragma unroll
    for (int f = 0; f < 4; ++f) af[f] = *(const short8*)((const char*)As + offA[f]);
#pragma unroll
    for (int f = 0; f < 4; ++f) bf[f] = *(const short8*)((const char*)Bs + offB[f]);
#pragma unroll
    for (int mf = 0; mf < 4; ++mf)
#pragma unroll
      for (int nf = 0; nf < 4; ++nf)
        acc[mf][nf] = MFMA16(af[mf], bf[nf], acc[mf][nf]);
  }

  const int colb = n0 + wn * 64 + la;
  const int rowb = m0 + wm * 64 + lg * 4;

  // add bias once (fp32)
#pragma unroll
  for (int nf = 0; nf < 4; ++nf) {
    const float bv = bias[colb + nf * 16];
#pragma unroll
    for (int mf = 0; mf < 4; ++mf)
#pragma unroll
      for (int r = 0; r < 4; ++r) acc[mf][nf][r] += bv;
  }

  if (MODE == 0) {
#pragma unroll
    for (int nf = 0; nf < 4; ++nf) {
      const int col = colb + nf * 16;
#pragma unroll
      for (int mf = 0; mf < 4; ++mf)
#pragma unroll
        for (int r = 0; r < 4; ++r)
          ((float*)Cout)[(size_t)(rowb + mf * 16 + r) * N + col] = acc[mf][nf][r];
    }
  } else {
    const int part = n0 >> 10;  // 0=q, 1=k, 2=v (col tile of 128 within one part)
    if (part < 2) {
      // fused RMSNorm: this wave's 64 cols = one head; rows are (mf,r)
      const float* nw = part ? knw : qnw;
      float nwv[4];
#pragma unroll
      for (int nf = 0; nf < 4; ++nf) nwv[nf] = nw[la + nf * 16];
#pragma unroll
      for (int mf = 0; mf < 4; ++mf)
#pragma unroll
        for (int r = 0; r < 4; ++r) {
          float ss = acc[mf][0][r] * acc[mf][0][r];
#pragma unroll
          for (int nf = 1; nf < 4; ++nf) ss = __builtin_fmaf(acc[mf][nf][r], acc[mf][nf][r], ss);
          ss += __shfl_xor(ss, 1); ss += __shfl_xor(ss, 2);
          ss += __shfl_xor(ss, 4); ss += __shfl_xor(ss, 8);
          const float rs = rsqrtf(ss * (1.f / 64.f) + 1e-6f);
#pragma unroll
          for (int nf = 0; nf < 4; ++nf) acc[mf][nf][r] *= rs * nwv[nf];
        }
#pragma unroll
      for (int nf = 0; nf < 4; ++nf) {
        const int col = colb + nf * 16;
#pragma unroll
        for (int mf = 0; mf < 4; ++mf)
#pragma unroll
          for (int r = 0; r < 4; ++r)
            ((unsigned short*)Cout)[(size_t)(rowb + mf * 16 + r) * N + col] = f2bf(acc[mf][nf][r]);
      }
    } else {
      // v: transpose-store to vT[(b*16+h)*64+d][n], 4 consecutive n per lane
#pragma unroll
      for (int nf = 0; nf < 4; ++nf) {
        const int col = colb + nf * 16;         // 2048 + h*64 + d
        const int h = (col >> 6) & 15;
        const int d = la + nf * 16;             // col & 63
#pragma unroll
        for (int mf = 0; mf < 4; ++mf) {
          const int row = rowb + mf * 16;       // rows row..row+3
          const int b = row >> 11, n = row & 2047;
          u16x4 o;
#pragma unroll
          for (int r = 0; r < 4; ++r) o[r] = f2bf(acc[mf][nf][r]);
          *(u16x4*)(vT + ((size_t)(b * 16 + h) * 64 + d) * 2048 + n) = o;
        }
      }
    }
  }
}

// ---------------------------------------------------------------------------
// 3) Flash attention, SPLIT-K over keys (grid.z = 2, 1024 keys each).
//    Static-max softmax makes partials additive: store raw fp32 accO + lsum.
//    Compute loop identical to the round-14 PASS kernel.
// ---------------------------------------------------------------------------
__global__ __launch_bounds__(256) void attn_fwd(
    const unsigned short* __restrict__ qkv, const unsigned short* __restrict__ vT,
    float* __restrict__ pO, float* __restrict__ pL) {
  __shared__ unsigned short Ks[64 * 64];
  __shared__ unsigned short Vs[64 * 64];
  __shared__ unsigned short Ps[4][16][76];
  const int t = threadIdx.x, w = t >> 6, l = t & 63;
  const int la = l & 15, lg = l >> 4;
  const int q0 = blockIdx.x * 64, bh = blockIdx.y, kh = blockIdx.z;
  const int b = bh >> 4, h = bh & 15;

  // Q fragment (B-operand of swapped QK^T: col=q=la, k=d=lg*8+j)
  const int qrow = q0 + w * 16 + la;
  const unsigned short* qp = qkv + (size_t)(b * 2048 + qrow) * 3072 + h * 64;
  const short8 qa0 = *(const short8*)(qp + lg * 8);
  const short8 qa1 = *(const short8*)(qp + 32 + lg * 8);

  // staging sources: 512 chunks/tile, rows of 8 chunks, swizzle c ^= (r&7)
  const int r0 = t >> 3, c0 = (t & 7) ^ (r0 & 7);
  const int r1 = r0 + 32, c1 = (t & 7) ^ (r1 & 7);
  const unsigned short* k0p = qkv + (size_t)(b * 2048 + r0) * 3072 + 1024 + h * 64 + c0 * 8;
  const unsigned short* k1p = qkv + (size_t)(b * 2048 + r1) * 3072 + 1024 + h * 64 + c1 * 8;
  const unsigned short* v0p = vT + (size_t)(bh * 64 + r0) * 2048 + c0 * 8;
  const unsigned short* v1p = vT + (size_t)(bh * 64 + r1) * 2048 + c1 * 8;

  f32x4 accO[4] = {};
  float lsum = 0.f;
  const float SC = 0.125f * 1.44269504f;  // scale * log2(e)
  const float M = 12.0f;                  // static max bound (|q.k|<=64.5 -> |s*SC|<=11.63)

  const int kbBeg = kh << 10, kbEnd = kbBeg + 1024;
  for (int kb = kbBeg; kb < kbEnd; kb += 64) {
    __syncthreads();
    load_lds16(k0p + (size_t)kb * 3072, (char*)Ks + w * 1024);
    load_lds16(k1p + (size_t)kb * 3072, (char*)Ks + w * 1024 + 4096);
    load_lds16(v0p + kb, (char*)Vs + w * 1024);
    load_lds16(v1p + kb, (char*)Vs + w * 1024 + 4096);
    __syncthreads();

    // S^T = K Q^T : A = K rows (keys), B = Q cols (q).
    f32x4 s[4] = {};
#pragma unroll
    for (int nf = 0; nf < 4; ++nf) {
      const int kr = nf * 16 + la;
      const short8 kf0 = *(const short8*)((const char*)Ks + kr * 128 + ((lg ^ (kr & 7)) * 16));
      const short8 kf1 = *(const short8*)((const char*)Ks + kr * 128 + (((4 + lg) ^ (kr & 7)) * 16));
      s[nf] = MFMA16(kf0, qa0, s[nf]);
      s[nf] = MFMA16(kf1, qa1, s[nf]);
    }
    // static-max softmax, lane-local; native exp2 + packed bf16 cvt
#pragma unroll
    for (int nf = 0; nf < 4; ++nf) {
      float e[4];
#pragma unroll
      for (int r = 0; r < 4; ++r)
        e[r] = __builtin_amdgcn_exp2f(__builtin_fmaf(s[nf][r], SC, -M));
      lsum += (e[0] + e[1]) + (e[2] + e[3]);
      union { __hip_bfloat162 hh[2]; u16x4 v; } pk;
      pk.hh[0] = __float22bfloat162_rn(float2{e[0], e[1]});
      pk.hh[1] = __float22bfloat162_rn(float2{e[2], e[3]});
      *(u16x4*)&Ps[w][la][nf * 16 + lg * 4] = pk.v;  // row=q(la), col=key
    }
    // compiler fence: forbid hoisting P reads above P writes (same-wave LDS RAW)
    asm volatile("" ::: "memory");
    // P A-fragments (row=q=la, k=key=lg*8+j)
    const short8 pa0 = *(const short8*)&Ps[w][la][lg * 8];
    const short8 pa1 = *(const short8*)&Ps[w][la][32 + lg * 8];

    // out += P V : P as A (rows q), V^T rows as B (cols d), K=32 x2
#pragma unroll
    for (int df = 0; df < 4; ++df) {
      const int vr = df * 16 + la;
      const short8 vf0 = *(const short8*)((const char*)Vs + vr * 128 + ((lg ^ (vr & 7)) * 16));
      const short8 vf1 = *(const short8*)((const char*)Vs + vr * 128 + (((4 + lg) ^ (vr & 7)) * 16));
      accO[df] = MFMA16(pa0, vf0, accO[df]);
      accO[df] = MFMA16(pa1, vf1, accO[df]);
    }
  }
  // partial store: raw accO (fp32) + per-row lsum
  lsum += __shfl_xor(lsum, 16);
  lsum += __shfl_xor(lsum, 32);
  const size_t base = ((size_t)(kh * 32 + bh) * 2048);
  if (lg == 0) pL[base + q0 + w * 16 + la] = lsum;
#pragma unroll
  for (int r = 0; r < 4; ++r) {
    const int orow = q0 + w * 16 + lg * 4 + r;
    float* op = pO + (base + orow) * 64 + la;
#pragma unroll
    for (int df = 0; df < 4; ++df) op[df * 16] = accO[df][r];
  }
}

// ---------------------------------------------------------------------------
// 4) Combine split-K partials: out = (A0+A1)/(l0+l1), bf16.
//    unit u = ((b*16+h)*2048 + n)*8 + d8 ; thread handles 8 d's.
// ---------------------------------------------------------------------------
__global__ __launch_bounds__(256) void attn_combine(
    const float* __restrict__ pO, const float* __restrict__ pL,
    unsigned short* __restrict__ outb) {
  const int u = blockIdx.x * 256 + threadIdx.x;  // 524288 units
  const int bhn = u >> 3, d8 = u & 7;
  const int bh = bhn >> 11, n = bhn & 2047;
  const int b = bh >> 4, h = bh & 15;
  const float* a0 = pO + (size_t)bhn * 64 + d8 * 8;
  const float* a1 = a0 + (size_t)32 * 2048 * 64;
  const float inv = 1.f / (pL[bhn] + pL[bhn + 32 * 2048]);
  float4 x0 = *(const float4*)a0, x1 = *(const float4*)(a0 + 4);
  float4 y0 = *(const float4*)a1, y1 = *(const float4*)(a1 + 4);
  ushort8 o;
  o[0] = f2bf((x0.x + y0.x) * inv); o[1] = f2bf((x0.y + y0.y) * inv);
  o[2] = f2bf((x0.z + y0.z) * inv); o[3] = f2bf((x0.w + y0.w) * inv);
  o[4] = f2bf((x1.x + y1.x) * inv); o[5] = f2bf((x1.y + y1.y) * inv);
  o[6] = f2bf((x1.z + y1.z) * inv); o[7] = f2bf((x1.w + y1.w) * inv);
  *(ushort8*)(outb + (size_t)(b * 2048 + n) * 1024 + h * 64 + d8 * 8) = o;
}

// ---------------------------------------------------------------------------
extern "C" void kernel_launch(void* const* d_in, const int* in_sizes, int n_in,
                              void* d_out, int out_size, void* d_ws, size_t ws_size,
                              hipStream_t stream) {
  const float* x     = (const float*)d_in[0];
  const float* wqkv  = (const float*)d_in[1];
  const float* bqkv  = (const float*)d_in[2];
  const float* qnw   = (const float*)d_in[3];
  const float* knw   = (const float*)d_in[4];
  const float* wproj = (const float*)d_in[5];
  const float* bproj = (const float*)d_in[6];

  char* p = (char*)d_ws;
  unsigned short* xb     = (unsigned short*)p; p += (size_t)4096 * 1024 * 2;  // 8 MB
  unsigned short* wqkvb  = (unsigned short*)p; p += (size_t)3072 * 1024 * 2;  // 6 MB
  unsigned short* wprojb = (unsigned short*)p; p += (size_t)1024 * 1024 * 2;  // 2 MB
  unsigned short* qkvb   = (unsigned short*)p; p += (size_t)4096 * 3072 * 2;  // 24 MB
  unsigned short* vT     = (unsigned short*)p; p += (size_t)32 * 64 * 2048 * 2; // 8 MB
  unsigned short* aout   = (unsigned short*)p; p += (size_t)4096 * 1024 * 2;  // 8 MB
  float*          pO     = (float*)p;          p += (size_t)2 * 32 * 2048 * 64 * 4; // 33.6 MB
  float*          pL     = (float*)p;          p += (size_t)2 * 32 * 2048 * 4;      // 0.5 MB

  convert_all<<<8192, 256, 0, stream>>>(x, wqkv, wproj, xb, wqkvb, wprojb);
  gemm_nt<1><<<dim3(24, 32), 256, 0, stream>>>(xb, wqkvb, bqkv, qkvb, 4096, 3072, 1024,
                                               qnw, knw, vT);
  attn_fwd<<<dim3(32, 32, 2), 256, 0, stream>>>(qkvb, vT, pO, pL);
  attn_combine<<<2048, 256, 0, stream>>>(pO, pL, aout);
  gemm_nt<0><<<dim3(8, 32), 256, 0, stream>>>(aout, wprojb, bproj, d_out, 4096, 1024, 1024,
                                              nullptr, nullptr, nullptr);
}

// Round 17
// 133.855 us; speedup vs baseline: 1.0386x; 1.0386x over previous
//
#include <hip/hip_runtime.h>
#include <hip/hip_bf16.h>

typedef __attribute__((ext_vector_type(8))) short short8;           // 8 bf16 (MFMA operand)
typedef __attribute__((ext_vector_type(8))) unsigned short ushort8; // data movement
typedef __attribute__((ext_vector_type(4))) float f32x4;
typedef __attribute__((ext_vector_type(4))) unsigned short u16x4;

#define MFMA16(a, b, c) __builtin_amdgcn_mfma_f32_16x16x32_bf16(a, b, c, 0, 0, 0)

__device__ __forceinline__ unsigned short f2bf(float f) {
  union { float f; unsigned u; } x; x.f = f;
  unsigned r = x.u + 0x7FFFu + ((x.u >> 16) & 1u);  // RNE
  return (unsigned short)(r >> 16);
}
__device__ __forceinline__ float bf2f(unsigned short h) {
  union { unsigned u; float f; } x; x.u = ((unsigned)h) << 16;
  return x.f;
}
__device__ __forceinline__ void load_lds16(const void* g, void* l) {
  __builtin_amdgcn_global_load_lds((const __attribute__((address_space(1))) void*)g,
                                   (__attribute__((address_space(3))) void*)l, 16, 0, 0);
}

// ---------------------------------------------------------------------------
// 1) fp32 -> bf16 conversion for x, w_qkv, w_proj
// ---------------------------------------------------------------------------
__global__ __launch_bounds__(256) void convert_all(
    const float* __restrict__ x, const float* __restrict__ wqkv, const float* __restrict__ wproj,
    unsigned short* __restrict__ xb, unsigned short* __restrict__ wqkvb,
    unsigned short* __restrict__ wprojb) {
  int i = blockIdx.x * 256 + threadIdx.x;
  const float4* src; unsigned short* dst; int o;
  if (i < 1048576) { src = (const float4*)x; dst = xb; o = i; }
  else if (i < 1048576 + 786432) { src = (const float4*)wqkv; dst = wqkvb; o = i - 1048576; }
  else { src = (const float4*)wproj; dst = wprojb; o = i - (1048576 + 786432); }
  float4 v = src[o];
  u16x4 r; r.x = f2bf(v.x); r.y = f2bf(v.y); r.z = f2bf(v.z); r.w = f2bf(v.w);
  *(u16x4*)(dst + (size_t)o * 4) = r;
}

// ---------------------------------------------------------------------------
// 2) NT GEMM: C[M,N] = A[M,K]*B[N,K]^T + bias. 128x128 tile, BK=32, 4 waves.
//    MODE 0: fp32 C out (out-proj).
//    MODE 1: QKV fused epilogue — q/k parts: RMSNorm (fp32) -> bf16 qkv;
//            v part: direct transpose-store to vT[bh][d][n] (skip qkv write).
// ---------------------------------------------------------------------------
template <int MODE>
__global__ __launch_bounds__(256) void gemm_nt(
    const unsigned short* __restrict__ A, const unsigned short* __restrict__ Bm,
    const float* __restrict__ bias, void* __restrict__ Cout, int M, int N, int K,
    const float* __restrict__ qnw, const float* __restrict__ knw,
    unsigned short* __restrict__ vT) {
  __shared__ unsigned short As[128 * 32];
  __shared__ unsigned short Bs[128 * 32];
  const int t = threadIdx.x, w = t >> 6, l = t & 63;
  const int la = l & 15, lg = l >> 4;
  const int wm = w >> 1, wn = w & 1;
  const int m0 = blockIdx.y * 128, n0 = blockIdx.x * 128;

  const int r0 = t >> 2, c0 = (t & 3) ^ ((r0 >> 1) & 3);
  const int r1 = r0 + 64, c1 = (t & 3) ^ ((r1 >> 1) & 3);
  const unsigned short* a0 = A + (size_t)(m0 + r0) * K + c0 * 8;
  const unsigned short* a1 = A + (size_t)(m0 + r1) * K + c1 * 8;
  const unsigned short* b0 = Bm + (size_t)(n0 + r0) * K + c0 * 8;
  const unsigned short* b1 = Bm + (size_t)(n0 + r1) * K + c1 * 8;
  char* ldsA0 = (char*)As + w * 1024;
  char* ldsA1 = (char*)As + w * 1024 + 4096;
  char* ldsB0 = (char*)Bs + w * 1024;
  char* ldsB1 = (char*)Bs + w * 1024 + 4096;

  f32x4 acc[4][4] = {};
  int offA[4], offB[4];
#pragma unroll
  for (int f = 0; f < 4; ++f) {
    int ra = wm * 64 + f * 16 + la;
    offA[f] = ra * 64 + ((lg ^ ((ra >> 1) & 3)) * 16);
    int rb = wn * 64 + f * 16 + la;
    offB[f] = rb * 64 + ((lg ^ ((rb >> 1) & 3)) * 16);
  }

  for (int kt = 0; kt < K; kt += 32) {
    __syncthreads();
    load_lds16(a0 + kt, ldsA0);
    load_lds16(a1 + kt, ldsA1);
    load_lds16(b0 + kt, ldsB0);
    load_lds16(b1 + kt, ldsB1);
    __syncthreads();
    short8 af[4], bf[4];
#pragma unroll
    for (int f = 0; f < 4; ++f) af[f] = *(const short8*)((const char*)As + offA[f]);
#pragma unroll
    for (int f = 0; f < 4; ++f) bf[f] = *(const short8*)((const char*)Bs + offB[f]);
#pragma unroll
    for (int mf = 0; mf < 4; ++mf)
#pragma unroll
      for (int nf = 0; nf < 4; ++nf)
        acc[mf][nf] = MFMA16(af[mf], bf[nf], acc[mf][nf]);
  }

  const int colb = n0 + wn * 64 + la;
  const int rowb = m0 + wm * 64 + lg * 4;

  // add bias once (fp32)
#pragma unroll
  for (int nf = 0; nf < 4; ++nf) {
    const float bv = bias[colb + nf * 16];
#pragma unroll
    for (int mf = 0; mf < 4; ++mf)
#pragma unroll
      for (int r = 0; r < 4; ++r) acc[mf][nf][r] += bv;
  }

  if (MODE == 0) {
#pragma unroll
    for (int nf = 0; nf < 4; ++nf) {
      const int col = colb + nf * 16;
#pragma unroll
      for (int mf = 0; mf < 4; ++mf)
#pragma unroll
        for (int r = 0; r < 4; ++r)
          ((float*)Cout)[(size_t)(rowb + mf * 16 + r) * N + col] = acc[mf][nf][r];
    }
  } else {
    const int part = n0 >> 10;  // 0=q, 1=k, 2=v (col tile of 128 within one part)
    if (part < 2) {
      // fused RMSNorm: this wave's 64 cols = one head; rows are (mf,r)
      const float* nw = part ? knw : qnw;
      float nwv[4];
#pragma unroll
      for (int nf = 0; nf < 4; ++nf) nwv[nf] = nw[la + nf * 16];
#pragma unroll
      for (int mf = 0; mf < 4; ++mf)
#pragma unroll
        for (int r = 0; r < 4; ++r) {
          float ss = acc[mf][0][r] * acc[mf][0][r];
#pragma unroll
          for (int nf = 1; nf < 4; ++nf) ss = __builtin_fmaf(acc[mf][nf][r], acc[mf][nf][r], ss);
          ss += __shfl_xor(ss, 1); ss += __shfl_xor(ss, 2);
          ss += __shfl_xor(ss, 4); ss += __shfl_xor(ss, 8);
          const float rs = rsqrtf(ss * (1.f / 64.f) + 1e-6f);
#pragma unroll
          for (int nf = 0; nf < 4; ++nf) acc[mf][nf][r] *= rs * nwv[nf];
        }
#pragma unroll
      for (int nf = 0; nf < 4; ++nf) {
        const int col = colb + nf * 16;
#pragma unroll
        for (int mf = 0; mf < 4; ++mf)
#pragma unroll
          for (int r = 0; r < 4; ++r)
            ((unsigned short*)Cout)[(size_t)(rowb + mf * 16 + r) * N + col] = f2bf(acc[mf][nf][r]);
      }
    } else {
      // v: transpose-store to vT[(b*16+h)*64+d][n], 4 consecutive n per lane
#pragma unroll
      for (int nf = 0; nf < 4; ++nf) {
        const int col = colb + nf * 16;         // 2048 + h*64 + d
        const int h = (col >> 6) & 15;
        const int d = la + nf * 16;             // col & 63
#pragma unroll
        for (int mf = 0; mf < 4; ++mf) {
          const int row = rowb + mf * 16;       // rows row..row+3
          const int b = row >> 11, n = row & 2047;
          u16x4 o;
#pragma unroll
          for (int r = 0; r < 4; ++r) o[r] = f2bf(acc[mf][nf][r]);
          *(u16x4*)(vT + ((size_t)(b * 16 + h) * 64 + d) * 2048 + n) = o;
        }
      }
    }
  }
}

// ---------------------------------------------------------------------------
// 3) Flash attention — QBLK=128: each block does 128 q-rows (4 waves x 32 q,
//    2 q-groups of 16). Staged K/V tile feeds 2x the MFMAs per LDS byte
//    (K/V fragments reused across q-groups). Monolithic staging (proven).
//    Grid (16, 32) = 512 blocks. LDS = 8K + 8K + 19456 = 35840 B.
// ---------------------------------------------------------------------------
__global__ __launch_bounds__(256) void attn_fwd(
    const unsigned short* __restrict__ qkv, const unsigned short* __restrict__ vT,
    unsigned short* __restrict__ outb) {
  __shared__ unsigned short Ks[64 * 64];
  __shared__ unsigned short Vs[64 * 64];
  __shared__ unsigned short Ps[4][32][76];  // 152 B rows (r4/10/11-proven stride)
  const int t = threadIdx.x, w = t >> 6, l = t & 63;
  const int la = l & 15, lg = l >> 4;
  const int q0 = blockIdx.x * 128, bh = blockIdx.y;
  const int b = bh >> 4, h = bh & 15;

  // Q fragments for 2 q-groups (B-operand of swapped QK^T: col=q=la, k=d=lg*8+j)
  const unsigned short* qp0 = qkv + (size_t)(b * 2048 + q0 + w * 32 + la) * 3072 + h * 64;
  const short8 qa00 = *(const short8*)(qp0 + lg * 8);
  const short8 qa01 = *(const short8*)(qp0 + 32 + lg * 8);
  const short8 qa10 = *(const short8*)(qp0 + (size_t)16 * 3072 + lg * 8);
  const short8 qa11 = *(const short8*)(qp0 + (size_t)16 * 3072 + 32 + lg * 8);

  // staging sources: 512 chunks/tile, rows of 8 chunks, swizzle c ^= (r&7)
  const int r0 = t >> 3, c0 = (t & 7) ^ (r0 & 7);
  const int r1 = r0 + 32, c1 = (t & 7) ^ (r1 & 7);
  const unsigned short* k0p = qkv + (size_t)(b * 2048 + r0) * 3072 + 1024 + h * 64 + c0 * 8;
  const unsigned short* k1p = qkv + (size_t)(b * 2048 + r1) * 3072 + 1024 + h * 64 + c1 * 8;
  const unsigned short* v0p = vT + (size_t)(bh * 64 + r0) * 2048 + c0 * 8;
  const unsigned short* v1p = vT + (size_t)(bh * 64 + r1) * 2048 + c1 * 8;

  f32x4 accO[2][4] = {};
  float lsum[2] = {0.f, 0.f};
  const float SC = 0.125f * 1.44269504f;  // scale * log2(e)
  const float M = 12.0f;                  // static max bound (|q.k|<=64.5 -> |s*SC|<=11.63)

  for (int kb = 0; kb < 2048; kb += 64) {
    __syncthreads();
    load_lds16(k0p + (size_t)kb * 3072, (char*)Ks + w * 1024);
    load_lds16(k1p + (size_t)kb * 3072, (char*)Ks + w * 1024 + 4096);
    load_lds16(v0p + kb, (char*)Vs + w * 1024);
    load_lds16(v1p + kb, (char*)Vs + w * 1024 + 4096);
    __syncthreads();

    // S^T = K Q^T : K-frags read ONCE, used by both q-groups.
    f32x4 s[2][4] = {};
#pragma unroll
    for (int nf = 0; nf < 4; ++nf) {
      const int kr = nf * 16 + la;
      const short8 kf0 = *(const short8*)((const char*)Ks + kr * 128 + ((lg ^ (kr & 7)) * 16));
      const short8 kf1 = *(const short8*)((const char*)Ks + kr * 128 + (((4 + lg) ^ (kr & 7)) * 16));
      s[0][nf] = MFMA16(kf0, qa00, s[0][nf]);
      s[0][nf] = MFMA16(kf1, qa01, s[0][nf]);
      s[1][nf] = MFMA16(kf0, qa10, s[1][nf]);
      s[1][nf] = MFMA16(kf1, qa11, s[1][nf]);
    }
    // static-max softmax, lane-local; native exp2 + packed bf16 cvt
#pragma unroll
    for (int g = 0; g < 2; ++g)
#pragma unroll
      for (int nf = 0; nf < 4; ++nf) {
        float e[4];
#pragma unroll
        for (int r = 0; r < 4; ++r)
          e[r] = __builtin_amdgcn_exp2f(__builtin_fmaf(s[g][nf][r], SC, -M));
        lsum[g] += (e[0] + e[1]) + (e[2] + e[3]);
        union { __hip_bfloat162 hh[2]; u16x4 v; } pk;
        pk.hh[0] = __float22bfloat162_rn(float2{e[0], e[1]});
        pk.hh[1] = __float22bfloat162_rn(float2{e[2], e[3]});
        *(u16x4*)&Ps[w][g * 16 + la][nf * 16 + lg * 4] = pk.v;  // row=q, col=key
      }
    // compiler fence: forbid hoisting P reads above P writes (same-wave LDS RAW)
    asm volatile("" ::: "memory");
    // P A-fragments per q-group (row=q, k=key=lg*8+j)
    const short8 pa00 = *(const short8*)&Ps[w][la][lg * 8];
    const short8 pa01 = *(const short8*)&Ps[w][la][32 + lg * 8];
    const short8 pa10 = *(const short8*)&Ps[w][16 + la][lg * 8];
    const short8 pa11 = *(const short8*)&Ps[w][16 + la][32 + lg * 8];

    // out += P V : V-frags read ONCE, used by both q-groups.
#pragma unroll
    for (int df = 0; df < 4; ++df) {
      const int vr = df * 16 + la;
      const short8 vf0 = *(const short8*)((const char*)Vs + vr * 128 + ((lg ^ (vr & 7)) * 16));
      const short8 vf1 = *(const short8*)((const char*)Vs + vr * 128 + (((4 + lg) ^ (vr & 7)) * 16));
      accO[0][df] = MFMA16(pa00, vf0, accO[0][df]);
      accO[0][df] = MFMA16(pa01, vf1, accO[0][df]);
      accO[1][df] = MFMA16(pa10, vf0, accO[1][df]);
      accO[1][df] = MFMA16(pa11, vf1, accO[1][df]);
    }
  }
  // epilogue per q-group: reduce lsum lg-copies, broadcast to C-layout rows
#pragma unroll
  for (int g = 0; g < 2; ++g) {
    lsum[g] += __shfl_xor(lsum[g], 16);
    lsum[g] += __shfl_xor(lsum[g], 32);
  }
#pragma unroll
  for (int g = 0; g < 2; ++g)
#pragma unroll
    for (int r = 0; r < 4; ++r) {
      const float inv = 1.f / __shfl(lsum[g], lg * 4 + r);
      const int orow = q0 + w * 32 + g * 16 + lg * 4 + r;
      unsigned short* op = outb + (size_t)(b * 2048 + orow) * 1024 + h * 64 + la;
#pragma unroll
      for (int df = 0; df < 4; ++df) op[df * 16] = f2bf(accO[g][df][r] * inv);
    }
}

// ---------------------------------------------------------------------------
extern "C" void kernel_launch(void* const* d_in, const int* in_sizes, int n_in,
                              void* d_out, int out_size, void* d_ws, size_t ws_size,
                              hipStream_t stream) {
  const float* x     = (const float*)d_in[0];
  const float* wqkv  = (const float*)d_in[1];
  const float* bqkv  = (const float*)d_in[2];
  const float* qnw   = (const float*)d_in[3];
  const float* knw   = (const float*)d_in[4];
  const float* wproj = (const float*)d_in[5];
  const float* bproj = (const float*)d_in[6];

  char* p = (char*)d_ws;
  unsigned short* xb     = (unsigned short*)p; p += (size_t)4096 * 1024 * 2;  // 8 MB
  unsigned short* wqkvb  = (unsigned short*)p; p += (size_t)3072 * 1024 * 2;  // 6 MB
  unsigned short* wprojb = (unsigned short*)p; p += (size_t)1024 * 1024 * 2;  // 2 MB
  unsigned short* qkvb   = (unsigned short*)p; p += (size_t)4096 * 3072 * 2;  // 24 MB
  unsigned short* vT     = (unsigned short*)p; p += (size_t)32 * 64 * 2048 * 2; // 8 MB
  unsigned short* aout   = (unsigned short*)p; p += (size_t)4096 * 1024 * 2;  // 8 MB

  convert_all<<<8192, 256, 0, stream>>>(x, wqkv, wproj, xb, wqkvb, wprojb);
  gemm_nt<1><<<dim3(24, 32), 256, 0, stream>>>(xb, wqkvb, bqkv, qkvb, 4096, 3072, 1024,
                                               qnw, knw, vT);
  attn_fwd<<<dim3(16, 32), 256, 0, stream>>>(qkvb, vT, aout);
  gemm_nt<0><<<dim3(8, 32), 256, 0, stream>>>(aout, wprojb, bproj, d_out, 4096, 1024, 1024,
                                              nullptr, nullptr, nullptr);
}

// Round 21
// 133.646 us; speedup vs baseline: 1.0403x; 1.0016x over previous
//
#include <hip/hip_runtime.h>
#include <hip/hip_bf16.h>

typedef __attribute__((ext_vector_type(8))) short short8;           // 8 bf16 (MFMA operand)
typedef __attribute__((ext_vector_type(8))) unsigned short ushort8; // data movement
typedef __attribute__((ext_vector_type(4))) float f32x4;
typedef __attribute__((ext_vector_type(4))) unsigned short u16x4;

#define MFMA16(a, b, c) __builtin_amdgcn_mfma_f32_16x16x32_bf16(a, b, c, 0, 0, 0)

__device__ __forceinline__ unsigned short f2bf(float f) {
  union { float f; unsigned u; } x; x.f = f;
  unsigned r = x.u + 0x7FFFu + ((x.u >> 16) & 1u);  // RNE
  return (unsigned short)(r >> 16);
}
__device__ __forceinline__ float bf2f(unsigned short h) {
  union { unsigned u; float f; } x; x.u = ((unsigned)h) << 16;
  return x.f;
}
__device__ __forceinline__ void load_lds16(const void* g, void* l) {
  __builtin_amdgcn_global_load_lds((const __attribute__((address_space(1))) void*)g,
                                   (__attribute__((address_space(3))) void*)l, 16, 0, 0);
}

// ---------------------------------------------------------------------------
// 1) fp32 -> bf16 conversion for x, w_qkv, w_proj
// ---------------------------------------------------------------------------
__global__ __launch_bounds__(256) void convert_all(
    const float* __restrict__ x, const float* __restrict__ wqkv, const float* __restrict__ wproj,
    unsigned short* __restrict__ xb, unsigned short* __restrict__ wqkvb,
    unsigned short* __restrict__ wprojb) {
  int i = blockIdx.x * 256 + threadIdx.x;
  const float4* src; unsigned short* dst; int o;
  if (i < 1048576) { src = (const float4*)x; dst = xb; o = i; }
  else if (i < 1048576 + 786432) { src = (const float4*)wqkv; dst = wqkvb; o = i - 1048576; }
  else { src = (const float4*)wproj; dst = wprojb; o = i - (1048576 + 786432); }
  float4 v = src[o];
  u16x4 r; r.x = f2bf(v.x); r.y = f2bf(v.y); r.z = f2bf(v.z); r.w = f2bf(v.w);
  *(u16x4*)(dst + (size_t)o * 4) = r;
}

// ---------------------------------------------------------------------------
// 2) NT GEMM, BK=64: two proven BK=32 compute halves per barrier sandwich
//    (barrier pairs halved: 32->16 for QKV). Staging uses the attn-proven
//    64-elem-row geometry: rows of 8 chunks, swizzle c ^= (r&7), 0 conflicts.
//    MODE 0: fp32 C out (out-proj).
//    MODE 1: QKV fused epilogue — q/k: RMSNorm -> bf16 qkv; v: store vT.
// ---------------------------------------------------------------------------
template <int MODE>
__global__ __launch_bounds__(256) void gemm_nt(
    const unsigned short* __restrict__ A, const unsigned short* __restrict__ Bm,
    const float* __restrict__ bias, void* __restrict__ Cout, int M, int N, int K,
    const float* __restrict__ qnw, const float* __restrict__ knw,
    unsigned short* __restrict__ vT) {
  __shared__ unsigned short As[128 * 64];  // 16 KB, rows of 128 B
  __shared__ unsigned short Bs[128 * 64];  // 16 KB
  const int t = threadIdx.x, w = t >> 6, l = t & 63;
  const int la = l & 15, lg = l >> 4;
  const int wm = w >> 1, wn = w & 1;
  const int m0 = blockIdx.y * 128, n0 = blockIdx.x * 128;

  // staging: 1024 chunks (16B) per matrix; thread t covers slots t+256q.
  // slot s -> row s>>3, slot-col s&7 (= t&7); data col c = (t&7) ^ (row&7),
  // and row&7 = (t>>3)&7 for all quarters -> one source col per thread.
  const int r0 = t >> 3;
  const int c0e = ((t & 7) ^ (r0 & 7)) * 8;  // element offset of 16B chunk
  const unsigned short* aP = A + (size_t)(m0 + r0) * K + c0e;
  const unsigned short* bP = Bm + (size_t)(n0 + r0) * K + c0e;
  char* ldsA = (char*)As + w * 1024;
  char* ldsB = (char*)Bs + w * 1024;

  f32x4 acc[4][4] = {};
  int offA0[4], offA1[4], offB0[4], offB1[4];
#pragma unroll
  for (int f = 0; f < 4; ++f) {
    const int ra = wm * 64 + f * 16 + la;
    offA0[f] = ra * 128 + ((lg ^ (ra & 7)) * 16);
    offA1[f] = ra * 128 + (((4 + lg) ^ (ra & 7)) * 16);
    const int rb = wn * 64 + f * 16 + la;
    offB0[f] = rb * 128 + ((lg ^ (rb & 7)) * 16);
    offB1[f] = rb * 128 + (((4 + lg) ^ (rb & 7)) * 16);
  }

  for (int kt = 0; kt < K; kt += 64) {
    __syncthreads();
#pragma unroll
    for (int q = 0; q < 4; ++q) {
      load_lds16(aP + (size_t)q * 32 * K + kt, ldsA + q * 4096);
      load_lds16(bP + (size_t)q * 32 * K + kt, ldsB + q * 4096);
    }
    __syncthreads();
    // half 0: k in [kt, kt+32)
    {
      short8 af[4], bf[4];
#pragma unroll
      for (int f = 0; f < 4; ++f) af[f] = *(const short8*)((const char*)As + offA0[f]);
#pragma unroll
      for (int f = 0; f < 4; ++f) bf[f] = *(const short8*)((const char*)Bs + offB0[f]);
#pragma unroll
      for (int mf = 0; mf < 4; ++mf)
#pragma unroll
        for (int nf = 0; nf < 4; ++nf)
          acc[mf][nf] = MFMA16(af[mf], bf[nf], acc[mf][nf]);
    }
    // half 1: k in [kt+32, kt+64)
    {
      short8 af[4], bf[4];
#pragma unroll
      for (int f = 0; f < 4; ++f) af[f] = *(const short8*)((const char*)As + offA1[f]);
#pragma unroll
      for (int f = 0; f < 4; ++f) bf[f] = *(const short8*)((const char*)Bs + offB1[f]);
#pragma unroll
      for (int mf = 0; mf < 4; ++mf)
#pragma unroll
        for (int nf = 0; nf < 4; ++nf)
          acc[mf][nf] = MFMA16(af[mf], bf[nf], acc[mf][nf]);
    }
  }

  const int colb = n0 + wn * 64 + la;
  const int rowb = m0 + wm * 64 + lg * 4;

  // add bias once (fp32)
#pragma unroll
  for (int nf = 0; nf < 4; ++nf) {
    const float bv = bias[colb + nf * 16];
#pragma unroll
    for (int mf = 0; mf < 4; ++mf)
#pragma unroll
      for (int r = 0; r < 4; ++r) acc[mf][nf][r] += bv;
  }

  if (MODE == 0) {
#pragma unroll
    for (int nf = 0; nf < 4; ++nf) {
      const int col = colb + nf * 16;
#pragma unroll
      for (int mf = 0; mf < 4; ++mf)
#pragma unroll
        for (int r = 0; r < 4; ++r)
          ((float*)Cout)[(size_t)(rowb + mf * 16 + r) * N + col] = acc[mf][nf][r];
    }
  } else {
    const int part = n0 >> 10;  // 0=q, 1=k, 2=v (col tile of 128 within one part)
    if (part < 2) {
      // fused RMSNorm: this wave's 64 cols = one head; rows are (mf,r)
      const float* nw = part ? knw : qnw;
      float nwv[4];
#pragma unroll
      for (int nf = 0; nf < 4; ++nf) nwv[nf] = nw[la + nf * 16];
#pragma unroll
      for (int mf = 0; mf < 4; ++mf)
#pragma unroll
        for (int r = 0; r < 4; ++r) {
          float ss = acc[mf][0][r] * acc[mf][0][r];
#pragma unroll
          for (int nf = 1; nf < 4; ++nf) ss = __builtin_fmaf(acc[mf][nf][r], acc[mf][nf][r], ss);
          ss += __shfl_xor(ss, 1); ss += __shfl_xor(ss, 2);
          ss += __shfl_xor(ss, 4); ss += __shfl_xor(ss, 8);
          const float rs = rsqrtf(ss * (1.f / 64.f) + 1e-6f);
#pragma unroll
          for (int nf = 0; nf < 4; ++nf) acc[mf][nf][r] *= rs * nwv[nf];
        }
#pragma unroll
      for (int nf = 0; nf < 4; ++nf) {
        const int col = colb + nf * 16;
#pragma unroll
        for (int mf = 0; mf < 4; ++mf)
#pragma unroll
          for (int r = 0; r < 4; ++r)
            ((unsigned short*)Cout)[(size_t)(rowb + mf * 16 + r) * N + col] = f2bf(acc[mf][nf][r]);
      }
    } else {
      // v: transpose-store to vT[(b*16+h)*64+d][n], 4 consecutive n per lane
#pragma unroll
      for (int nf = 0; nf < 4; ++nf) {
        const int col = colb + nf * 16;         // 2048 + h*64 + d
        const int h = (col >> 6) & 15;
        const int d = la + nf * 16;             // col & 63
#pragma unroll
        for (int mf = 0; mf < 4; ++mf) {
          const int row = rowb + mf * 16;       // rows row..row+3
          const int b = row >> 11, n = row & 2047;
          u16x4 o;
#pragma unroll
          for (int r = 0; r < 4; ++r) o[r] = f2bf(acc[mf][nf][r]);
          *(u16x4*)(vT + ((size_t)(b * 16 + h) * 64 + d) * 2048 + n) = o;
        }
      }
    }
  }
}

// ---------------------------------------------------------------------------
// 3) Flash attention — round-14 PASS kernel verbatim (QBLK=64, proven 64.3us).
// ---------------------------------------------------------------------------
__global__ __launch_bounds__(256) void attn_fwd(
    const unsigned short* __restrict__ qkv, const unsigned short* __restrict__ vT,
    unsigned short* __restrict__ outb) {
  __shared__ unsigned short Ks[64 * 64];
  __shared__ unsigned short Vs[64 * 64];
  __shared__ unsigned short Ps[4][16][76];
  const int t = threadIdx.x, w = t >> 6, l = t & 63;
  const int la = l & 15, lg = l >> 4;
  const int q0 = blockIdx.x * 64, bh = blockIdx.y;
  const int b = bh >> 4, h = bh & 15;

  // Q fragment (B-operand of swapped QK^T: col=q=la, k=d=lg*8+j)
  const int qrow = q0 + w * 16 + la;
  const unsigned short* qp = qkv + (size_t)(b * 2048 + qrow) * 3072 + h * 64;
  const short8 qa0 = *(const short8*)(qp + lg * 8);
  const short8 qa1 = *(const short8*)(qp + 32 + lg * 8);

  // staging sources: 512 chunks/tile, rows of 8 chunks, swizzle c ^= (r&7)
  const int r0 = t >> 3, c0 = (t & 7) ^ (r0 & 7);
  const int r1 = r0 + 32, c1 = (t & 7) ^ (r1 & 7);
  const unsigned short* k0p = qkv + (size_t)(b * 2048 + r0) * 3072 + 1024 + h * 64 + c0 * 8;
  const unsigned short* k1p = qkv + (size_t)(b * 2048 + r1) * 3072 + 1024 + h * 64 + c1 * 8;
  const unsigned short* v0p = vT + (size_t)(bh * 64 + r0) * 2048 + c0 * 8;
  const unsigned short* v1p = vT + (size_t)(bh * 64 + r1) * 2048 + c1 * 8;

  f32x4 accO[4] = {};
  float lsum = 0.f;
  const float SC = 0.125f * 1.44269504f;  // scale * log2(e)
  const float M = 12.0f;                  // static max bound (|q.k|<=64.5 -> |s*SC|<=11.63)

  for (int kb = 0; kb < 2048; kb += 64) {
    __syncthreads();
    load_lds16(k0p + (size_t)kb * 3072, (char*)Ks + w * 1024);
    load_lds16(k1p + (size_t)kb * 3072, (char*)Ks + w * 1024 + 4096);
    load_lds16(v0p + kb, (char*)Vs + w * 1024);
    load_lds16(v1p + kb, (char*)Vs + w * 1024 + 4096);
    __syncthreads();

    // S^T = K Q^T : A = K rows (keys), B = Q cols (q).
    f32x4 s[4] = {};
#pragma unroll
    for (int nf = 0; nf < 4; ++nf) {
      const int kr = nf * 16 + la;
      const short8 kf0 = *(const short8*)((const char*)Ks + kr * 128 + ((lg ^ (kr & 7)) * 16));
      const short8 kf1 = *(const short8*)((const char*)Ks + kr * 128 + (((4 + lg) ^ (kr & 7)) * 16));
      s[nf] = MFMA16(kf0, qa0, s[nf]);
      s[nf] = MFMA16(kf1, qa1, s[nf]);
    }
    // static-max softmax, lane-local; native exp2 + packed bf16 cvt
#pragma unroll
    for (int nf = 0; nf < 4; ++nf) {
      float e[4];
#pragma unroll
      for (int r = 0; r < 4; ++r)
        e[r] = __builtin_amdgcn_exp2f(__builtin_fmaf(s[nf][r], SC, -M));
      lsum += (e[0] + e[1]) + (e[2] + e[3]);
      union { __hip_bfloat162 hh[2]; u16x4 v; } pk;
      pk.hh[0] = __float22bfloat162_rn(float2{e[0], e[1]});
      pk.hh[1] = __float22bfloat162_rn(float2{e[2], e[3]});
      *(u16x4*)&Ps[w][la][nf * 16 + lg * 4] = pk.v;  // row=q(la), col=key
    }
    // compiler fence: forbid hoisting P reads above P writes (same-wave LDS RAW)
    asm volatile("" ::: "memory");
    // P A-fragments (row=q=la, k=key=lg*8+j)
    const short8 pa0 = *(const short8*)&Ps[w][la][lg * 8];
    const short8 pa1 = *(const short8*)&Ps[w][la][32 + lg * 8];

    // out += P V : P as A (rows q), V^T rows as B (cols d), K=32 x2
#pragma unroll
    for (int df = 0; df < 4; ++df) {
      const int vr = df * 16 + la;
      const short8 vf0 = *(const short8*)((const char*)Vs + vr * 128 + ((lg ^ (vr & 7)) * 16));
      const short8 vf1 = *(const short8*)((const char*)Vs + vr * 128 + (((4 + lg) ^ (vr & 7)) * 16));
      accO[df] = MFMA16(pa0, vf0, accO[df]);
      accO[df] = MFMA16(pa1, vf1, accO[df]);
    }
  }
  // lsum: reduce the 4 lg-copies of q=la, broadcast to C-layout rows
  lsum += __shfl_xor(lsum, 16);
  lsum += __shfl_xor(lsum, 32);
#pragma unroll
  for (int r = 0; r < 4; ++r) {
    const float inv = 1.f / __shfl(lsum, lg * 4 + r);  // lane lg*4+r (la=lg*4+r) holds q's total
    const int orow = q0 + w * 16 + lg * 4 + r;
    unsigned short* op = outb + (size_t)(b * 2048 + orow) * 1024 + h * 64 + la;
#pragma unroll
    for (int df = 0; df < 4; ++df) op[df * 16] = f2bf(accO[df][r] * inv);
  }
}

// ---------------------------------------------------------------------------
extern "C" void kernel_launch(void* const* d_in, const int* in_sizes, int n_in,
                              void* d_out, int out_size, void* d_ws, size_t ws_size,
                              hipStream_t stream) {
  const float* x     = (const float*)d_in[0];
  const float* wqkv  = (const float*)d_in[1];
  const float* bqkv  = (const float*)d_in[2];
  const float* qnw   = (const float*)d_in[3];
  const float* knw   = (const float*)d_in[4];
  const float* wproj = (const float*)d_in[5];
  const float* bproj = (const float*)d_in[6];

  char* p = (char*)d_ws;
  unsigned short* xb     = (unsigned short*)p; p += (size_t)4096 * 1024 * 2;  // 8 MB
  unsigned short* wqkvb  = (unsigned short*)p; p += (size_t)3072 * 1024 * 2;  // 6 MB
  unsigned short* wprojb = (unsigned short*)p; p += (size_t)1024 * 1024 * 2;  // 2 MB
  unsigned short* qkvb   = (unsigned short*)p; p += (size_t)4096 * 3072 * 2;  // 24 MB
  unsigned short* vT     = (unsigned short*)p; p += (size_t)32 * 64 * 2048 * 2; // 8 MB
  unsigned short* aout   = (unsigned short*)p; p += (size_t)4096 * 1024 * 2;  // 8 MB

  convert_all<<<8192, 256, 0, stream>>>(x, wqkv, wproj, xb, wqkvb, wprojb);
  gemm_nt<1><<<dim3(24, 32), 256, 0, stream>>>(xb, wqkvb, bqkv, qkvb, 4096, 3072, 1024,
                                               qnw, knw, vT);
  attn_fwd<<<dim3(32, 32), 256, 0, stream>>>(qkvb, vT, aout);
  gemm_nt<0><<<dim3(8, 32), 256, 0, stream>>>(aout, wprojb, bproj, d_out, 4096, 1024, 1024,
                                              nullptr, nullptr, nullptr);
}

// Round 22
// 133.553 us; speedup vs baseline: 1.0410x; 1.0007x over previous
//
#include <hip/hip_runtime.h>
#include <hip/hip_bf16.h>

typedef __attribute__((ext_vector_type(8))) short short8;           // 8 bf16 (MFMA operand)
typedef __attribute__((ext_vector_type(8))) unsigned short ushort8; // data movement
typedef __attribute__((ext_vector_type(4))) float f32x4;
typedef __attribute__((ext_vector_type(4))) unsigned short u16x4;

#define MFMA16(a, b, c) __builtin_amdgcn_mfma_f32_16x16x32_bf16(a, b, c, 0, 0, 0)

__device__ __forceinline__ unsigned short f2bf(float f) {
  union { float f; unsigned u; } x; x.f = f;
  unsigned r = x.u + 0x7FFFu + ((x.u >> 16) & 1u);  // RNE
  return (unsigned short)(r >> 16);
}
__device__ __forceinline__ float bf2f(unsigned short h) {
  union { unsigned u; float f; } x; x.u = ((unsigned)h) << 16;
  return x.f;
}
__device__ __forceinline__ void load_lds16(const void* g, void* l) {
  __builtin_amdgcn_global_load_lds((const __attribute__((address_space(1))) void*)g,
                                   (__attribute__((address_space(3))) void*)l, 16, 0, 0);
}

// ---------------------------------------------------------------------------
// 1) fp32 -> bf16 conversion for x, w_qkv, w_proj
// ---------------------------------------------------------------------------
__global__ __launch_bounds__(256) void convert_all(
    const float* __restrict__ x, const float* __restrict__ wqkv, const float* __restrict__ wproj,
    unsigned short* __restrict__ xb, unsigned short* __restrict__ wqkvb,
    unsigned short* __restrict__ wprojb) {
  int i = blockIdx.x * 256 + threadIdx.x;
  const float4* src; unsigned short* dst; int o;
  if (i < 1048576) { src = (const float4*)x; dst = xb; o = i; }
  else if (i < 1048576 + 786432) { src = (const float4*)wqkv; dst = wqkvb; o = i - 1048576; }
  else { src = (const float4*)wproj; dst = wprojb; o = i - (1048576 + 786432); }
  float4 v = src[o];
  u16x4 r; r.x = f2bf(v.x); r.y = f2bf(v.y); r.z = f2bf(v.z); r.w = f2bf(v.w);
  *(u16x4*)(dst + (size_t)o * 4) = r;
}

// ---------------------------------------------------------------------------
// 2) NT GEMM, BK=64 (r21-proven) + XCD-aware block swizzle (T1):
//    consecutive original bids land on the same XCD's L2 -> blocks sharing an
//    A-panel co-reside; per-XCD L2 traffic ~halves. Compute bit-identical.
//    MODE 0: fp32 C out (out-proj). MODE 1: QKV fused epilogue.
// ---------------------------------------------------------------------------
template <int MODE>
__global__ __launch_bounds__(256) void gemm_nt(
    const unsigned short* __restrict__ A, const unsigned short* __restrict__ Bm,
    const float* __restrict__ bias, void* __restrict__ Cout, int M, int N, int K,
    const float* __restrict__ qnw, const float* __restrict__ knw,
    unsigned short* __restrict__ vT) {
  __shared__ unsigned short As[128 * 64];  // 16 KB, rows of 128 B
  __shared__ unsigned short Bs[128 * 64];  // 16 KB
  const int t = threadIdx.x, w = t >> 6, l = t & 63;
  const int la = l & 15, lg = l >> 4;
  const int wm = w >> 1, wn = w & 1;
  // XCD swizzle: bid%8 = XCD (dispatch round-robin); give XCD k a contiguous
  // swz-chunk so its blocks share A-panels. Bijective (nwg % 8 == 0).
  const int nwgx = gridDim.x;
  const int bid = blockIdx.y * nwgx + blockIdx.x;
  const int cpx = (nwgx * gridDim.y) >> 3;
  const int swz = (bid & 7) * cpx + (bid >> 3);
  const int m0 = (swz / nwgx) * 128, n0 = (swz % nwgx) * 128;

  const int r0 = t >> 3;
  const int c0e = ((t & 7) ^ (r0 & 7)) * 8;  // element offset of 16B chunk
  const unsigned short* aP = A + (size_t)(m0 + r0) * K + c0e;
  const unsigned short* bP = Bm + (size_t)(n0 + r0) * K + c0e;
  char* ldsA = (char*)As + w * 1024;
  char* ldsB = (char*)Bs + w * 1024;

  f32x4 acc[4][4] = {};
  int offA0[4], offA1[4], offB0[4], offB1[4];
#pragma unroll
  for (int f = 0; f < 4; ++f) {
    const int ra = wm * 64 + f * 16 + la;
    offA0[f] = ra * 128 + ((lg ^ (ra & 7)) * 16);
    offA1[f] = ra * 128 + (((4 + lg) ^ (ra & 7)) * 16);
    const int rb = wn * 64 + f * 16 + la;
    offB0[f] = rb * 128 + ((lg ^ (rb & 7)) * 16);
    offB1[f] = rb * 128 + (((4 + lg) ^ (rb & 7)) * 16);
  }

  for (int kt = 0; kt < K; kt += 64) {
    __syncthreads();
#pragma unroll
    for (int q = 0; q < 4; ++q) {
      load_lds16(aP + (size_t)q * 32 * K + kt, ldsA + q * 4096);
      load_lds16(bP + (size_t)q * 32 * K + kt, ldsB + q * 4096);
    }
    __syncthreads();
    // half 0: k in [kt, kt+32)
    {
      short8 af[4], bf[4];
#pragma unroll
      for (int f = 0; f < 4; ++f) af[f] = *(const short8*)((const char*)As + offA0[f]);
#pragma unroll
      for (int f = 0; f < 4; ++f) bf[f] = *(const short8*)((const char*)Bs + offB0[f]);
#pragma unroll
      for (int mf = 0; mf < 4; ++mf)
#pragma unroll
        for (int nf = 0; nf < 4; ++nf)
          acc[mf][nf] = MFMA16(af[mf], bf[nf], acc[mf][nf]);
    }
    // half 1: k in [kt+32, kt+64)
    {
      short8 af[4], bf[4];
#pragma unroll
      for (int f = 0; f < 4; ++f) af[f] = *(const short8*)((const char*)As + offA1[f]);
#pragma unroll
      for (int f = 0; f < 4; ++f) bf[f] = *(const short8*)((const char*)Bs + offB1[f]);
#pragma unroll
      for (int mf = 0; mf < 4; ++mf)
#pragma unroll
        for (int nf = 0; nf < 4; ++nf)
          acc[mf][nf] = MFMA16(af[mf], bf[nf], acc[mf][nf]);
    }
  }

  const int colb = n0 + wn * 64 + la;
  const int rowb = m0 + wm * 64 + lg * 4;

  // add bias once (fp32)
#pragma unroll
  for (int nf = 0; nf < 4; ++nf) {
    const float bv = bias[colb + nf * 16];
#pragma unroll
    for (int mf = 0; mf < 4; ++mf)
#pragma unroll
      for (int r = 0; r < 4; ++r) acc[mf][nf][r] += bv;
  }

  if (MODE == 0) {
#pragma unroll
    for (int nf = 0; nf < 4; ++nf) {
      const int col = colb + nf * 16;
#pragma unroll
      for (int mf = 0; mf < 4; ++mf)
#pragma unroll
        for (int r = 0; r < 4; ++r)
          ((float*)Cout)[(size_t)(rowb + mf * 16 + r) * N + col] = acc[mf][nf][r];
    }
  } else {
    const int part = n0 >> 10;  // 0=q, 1=k, 2=v (col tile of 128 within one part)
    if (part < 2) {
      // fused RMSNorm: this wave's 64 cols = one head; rows are (mf,r)
      const float* nw = part ? knw : qnw;
      float nwv[4];
#pragma unroll
      for (int nf = 0; nf < 4; ++nf) nwv[nf] = nw[la + nf * 16];
#pragma unroll
      for (int mf = 0; mf < 4; ++mf)
#pragma unroll
        for (int r = 0; r < 4; ++r) {
          float ss = acc[mf][0][r] * acc[mf][0][r];
#pragma unroll
          for (int nf = 1; nf < 4; ++nf) ss = __builtin_fmaf(acc[mf][nf][r], acc[mf][nf][r], ss);
          ss += __shfl_xor(ss, 1); ss += __shfl_xor(ss, 2);
          ss += __shfl_xor(ss, 4); ss += __shfl_xor(ss, 8);
          const float rs = rsqrtf(ss * (1.f / 64.f) + 1e-6f);
#pragma unroll
          for (int nf = 0; nf < 4; ++nf) acc[mf][nf][r] *= rs * nwv[nf];
        }
#pragma unroll
      for (int nf = 0; nf < 4; ++nf) {
        const int col = colb + nf * 16;
#pragma unroll
        for (int mf = 0; mf < 4; ++mf)
#pragma unroll
          for (int r = 0; r < 4; ++r)
            ((unsigned short*)Cout)[(size_t)(rowb + mf * 16 + r) * N + col] = f2bf(acc[mf][nf][r]);
      }
    } else {
      // v: transpose-store to vT[(b*16+h)*64+d][n], 4 consecutive n per lane
#pragma unroll
      for (int nf = 0; nf < 4; ++nf) {
        const int col = colb + nf * 16;         // 2048 + h*64 + d
        const int h = (col >> 6) & 15;
        const int d = la + nf * 16;             // col & 63
#pragma unroll
        for (int mf = 0; mf < 4; ++mf) {
          const int row = rowb + mf * 16;       // rows row..row+3
          const int b = row >> 11, n = row & 2047;
          u16x4 o;
#pragma unroll
          for (int r = 0; r < 4; ++r) o[r] = f2bf(acc[mf][nf][r]);
          *(u16x4*)(vT + ((size_t)(b * 16 + h) * 64 + d) * 2048 + n) = o;
        }
      }
    }
  }
}

// ---------------------------------------------------------------------------
// 3) Flash attention — r14-proven compute + XCD swizzle: XCD k owns 4
//    consecutive (b,h) heads -> their K/V panels (2 MB) stay L2-resident.
// ---------------------------------------------------------------------------
__global__ __launch_bounds__(256) void attn_fwd(
    const unsigned short* __restrict__ qkv, const unsigned short* __restrict__ vT,
    unsigned short* __restrict__ outb) {
  __shared__ unsigned short Ks[64 * 64];
  __shared__ unsigned short Vs[64 * 64];
  __shared__ unsigned short Ps[4][16][76];
  const int t = threadIdx.x, w = t >> 6, l = t & 63;
  const int la = l & 15, lg = l >> 4;
  // XCD swizzle over the 1024-block grid (32 q-blocks x 32 bh)
  const int bid = blockIdx.y * 32 + blockIdx.x;
  const int swz = (bid & 7) * 128 + (bid >> 3);
  const int q0 = (swz & 31) * 64, bh = swz >> 5;
  const int b = bh >> 4, h = bh & 15;

  // Q fragment (B-operand of swapped QK^T: col=q=la, k=d=lg*8+j)
  const int qrow = q0 + w * 16 + la;
  const unsigned short* qp = qkv + (size_t)(b * 2048 + qrow) * 3072 + h * 64;
  const short8 qa0 = *(const short8*)(qp + lg * 8);
  const short8 qa1 = *(const short8*)(qp + 32 + lg * 8);

  // staging sources: 512 chunks/tile, rows of 8 chunks, swizzle c ^= (r&7)
  const int r0 = t >> 3, c0 = (t & 7) ^ (r0 & 7);
  const int r1 = r0 + 32, c1 = (t & 7) ^ (r1 & 7);
  const unsigned short* k0p = qkv + (size_t)(b * 2048 + r0) * 3072 + 1024 + h * 64 + c0 * 8;
  const unsigned short* k1p = qkv + (size_t)(b * 2048 + r1) * 3072 + 1024 + h * 64 + c1 * 8;
  const unsigned short* v0p = vT + (size_t)(bh * 64 + r0) * 2048 + c0 * 8;
  const unsigned short* v1p = vT + (size_t)(bh * 64 + r1) * 2048 + c1 * 8;

  f32x4 accO[4] = {};
  float lsum = 0.f;
  const float SC = 0.125f * 1.44269504f;  // scale * log2(e)
  const float M = 12.0f;                  // static max bound (|q.k|<=64.5 -> |s*SC|<=11.63)

  for (int kb = 0; kb < 2048; kb += 64) {
    __syncthreads();
    load_lds16(k0p + (size_t)kb * 3072, (char*)Ks + w * 1024);
    load_lds16(k1p + (size_t)kb * 3072, (char*)Ks + w * 1024 + 4096);
    load_lds16(v0p + kb, (char*)Vs + w * 1024);
    load_lds16(v1p + kb, (char*)Vs + w * 1024 + 4096);
    __syncthreads();

    // S^T = K Q^T : A = K rows (keys), B = Q cols (q).
    f32x4 s[4] = {};
#pragma unroll
    for (int nf = 0; nf < 4; ++nf) {
      const int kr = nf * 16 + la;
      const short8 kf0 = *(const short8*)((const char*)Ks + kr * 128 + ((lg ^ (kr & 7)) * 16));
      const short8 kf1 = *(const short8*)((const char*)Ks + kr * 128 + (((4 + lg) ^ (kr & 7)) * 16));
      s[nf] = MFMA16(kf0, qa0, s[nf]);
      s[nf] = MFMA16(kf1, qa1, s[nf]);
    }
    // static-max softmax, lane-local; native exp2 + packed bf16 cvt
#pragma unroll
    for (int nf = 0; nf < 4; ++nf) {
      float e[4];
#pragma unroll
      for (int r = 0; r < 4; ++r)
        e[r] = __builtin_amdgcn_exp2f(__builtin_fmaf(s[nf][r], SC, -M));
      lsum += (e[0] + e[1]) + (e[2] + e[3]);
      union { __hip_bfloat162 hh[2]; u16x4 v; } pk;
      pk.hh[0] = __float22bfloat162_rn(float2{e[0], e[1]});
      pk.hh[1] = __float22bfloat162_rn(float2{e[2], e[3]});
      *(u16x4*)&Ps[w][la][nf * 16 + lg * 4] = pk.v;  // row=q(la), col=key
    }
    // compiler fence: forbid hoisting P reads above P writes (same-wave LDS RAW)
    asm volatile("" ::: "memory");
    // P A-fragments (row=q=la, k=key=lg*8+j)
    const short8 pa0 = *(const short8*)&Ps[w][la][lg * 8];
    const short8 pa1 = *(const short8*)&Ps[w][la][32 + lg * 8];

    // out += P V : P as A (rows q), V^T rows as B (cols d), K=32 x2
#pragma unroll
    for (int df = 0; df < 4; ++df) {
      const int vr = df * 16 + la;
      const short8 vf0 = *(const short8*)((const char*)Vs + vr * 128 + ((lg ^ (vr & 7)) * 16));
      const short8 vf1 = *(const short8*)((const char*)Vs + vr * 128 + (((4 + lg) ^ (vr & 7)) * 16));
      accO[df] = MFMA16(pa0, vf0, accO[df]);
      accO[df] = MFMA16(pa1, vf1, accO[df]);
    }
  }
  // lsum: reduce the 4 lg-copies of q=la, broadcast to C-layout rows
  lsum += __shfl_xor(lsum, 16);
  lsum += __shfl_xor(lsum, 32);
#pragma unroll
  for (int r = 0; r < 4; ++r) {
    const float inv = 1.f / __shfl(lsum, lg * 4 + r);  // lane lg*4+r (la=lg*4+r) holds q's total
    const int orow = q0 + w * 16 + lg * 4 + r;
    unsigned short* op = outb + (size_t)(b * 2048 + orow) * 1024 + h * 64 + la;
#pragma unroll
    for (int df = 0; df < 4; ++df) op[df * 16] = f2bf(accO[df][r] * inv);
  }
}

// ---------------------------------------------------------------------------
extern "C" void kernel_launch(void* const* d_in, const int* in_sizes, int n_in,
                              void* d_out, int out_size, void* d_ws, size_t ws_size,
                              hipStream_t stream) {
  const float* x     = (const float*)d_in[0];
  const float* wqkv  = (const float*)d_in[1];
  const float* bqkv  = (const float*)d_in[2];
  const float* qnw   = (const float*)d_in[3];
  const float* knw   = (const float*)d_in[4];
  const float* wproj = (const float*)d_in[5];
  const float* bproj = (const float*)d_in[6];

  char* p = (char*)d_ws;
  unsigned short* xb     = (unsigned short*)p; p += (size_t)4096 * 1024 * 2;  // 8 MB
  unsigned short* wqkvb  = (unsigned short*)p; p += (size_t)3072 * 1024 * 2;  // 6 MB
  unsigned short* wprojb = (unsigned short*)p; p += (size_t)1024 * 1024 * 2;  // 2 MB
  unsigned short* qkvb   = (unsigned short*)p; p += (size_t)4096 * 3072 * 2;  // 24 MB
  unsigned short* vT     = (unsigned short*)p; p += (size_t)32 * 64 * 2048 * 2; // 8 MB
  unsigned short* aout   = (unsigned short*)p; p += (size_t)4096 * 1024 * 2;  // 8 MB

  convert_all<<<8192, 256, 0, stream>>>(x, wqkv, wproj, xb, wqkvb, wprojb);
  gemm_nt<1><<<dim3(24, 32), 256, 0, stream>>>(xb, wqkvb, bqkv, qkvb, 4096, 3072, 1024,
                                               qnw, knw, vT);
  attn_fwd<<<dim3(32, 32), 256, 0, stream>>>(qkvb, vT, aout);
  gemm_nt<0><<<dim3(8, 32), 256, 0, stream>>>(aout, wprojb, bproj, d_out, 4096, 1024, 1024,
                                              nullptr, nullptr, nullptr);
}